// Round 6
// baseline (15.250 us; speedup 1.0000x reference)
//
#include <hip/hip_runtime.h>

#define NGT 64
#define NUM_CLASSES_F 80.0f
#define INF_F 100000000.0f
#define RADIUS_F 1.5f

__global__ __launch_bounds__(256, 8) void fcos_match_kernel(
    const float* __restrict__ locations,      // (L,2)
    const float* __restrict__ strides_per_loc,// (L,)
    const float* __restrict__ soi,            // (L,2)
    const float* __restrict__ anchors,        // (L,4)
    const float* __restrict__ gt_boxes,       // (B,G,4)
    const int*   __restrict__ gt_classes,     // (B,G)
    float* __restrict__ out,                  // cls (B*L) | reg (B*L*4) | deltas (B*L*4)
    int L, int B)
{
    const int b = blockIdx.y;

    __shared__ float4 sbox[NGT];
    __shared__ float  sclsf[NGT];
    if (threadIdx.x < NGT) {
        const int j = threadIdx.x;
        sbox[j]  = reinterpret_cast<const float4*>(gt_boxes)[b * NGT + j];
        sclsf[j] = (float)gt_classes[b * NGT + j];
    }
    __syncthreads();

    // 4 threads per location; thread k scans boxes j = 4s+k (interleaved ->
    // the wave's 4 concurrent ds_read_b128 addresses hit 16 distinct banks).
    const int  k      = threadIdx.x & 3;
    const int  p      = blockIdx.x * 64 + (threadIdx.x >> 2);
    const bool active = p < L;
    const int  i      = active ? p : 0;

    const float2 xy   = reinterpret_cast<const float2*>(locations)[i];
    const float  x    = xy.x, y = xy.y;
    const float  rad  = strides_per_loc[i] * RADIUS_F;
    const float2 lohi = reinterpret_cast<const float2*>(soi)[i];

    float minv = INF_F;
    int   ind  = k;            // j = 4*0 + k

    #pragma unroll
    for (int s = 0; s < 16; ++s) {
        const int jg = (s << 2) | k;
        const float4 bx = sbox[jg];

        const float l = x - bx.x, t = y - bx.y;
        const float r = bx.z - x, d = bx.w - y;
        const float mx = fmaxf(fmaxf(fmaxf(l, t), r), d);   // max3+max
        const float mn = fminf(fminf(fminf(l, t), r), d);   // min3+min

        // identical rounding path to R4/R5 (validated absmax 0.0)
        const float ccx = (bx.x + bx.z) * 0.5f;
        const float ccy = (bx.y + bx.w) * 0.5f;
        const float cx  = rad - fabsf(x - ccx);
        const float cy  = rad - fabsf(y - ccy);
        const float cmin = fminf(fminf(mn, cx), cy);        // min3

        const float g    = fminf(mx - lohi.x, lohi.y - mx);
        const float area = (bx.z - bx.x) * (bx.w - bx.y);
        const float v = ((cmin > 0.0f) && (g >= 0.0f)) ? area : INF_F;
        if (v < minv) { minv = v; ind = jg; }
    }

    // Lexicographic (v, ind) butterfly over the 4-lane group:
    // min index among minimal v == first-occurrence argmin (all-INF -> 0).
    {
        float vp = __shfl_xor(minv, 1);
        int   ip = __shfl_xor(ind, 1);
        if (vp < minv || (vp == minv && ip < ind)) { minv = vp; ind = ip; }
        vp = __shfl_xor(minv, 2);
        ip = __shfl_xor(ind, 2);
        if (vp < minv || (vp == minv && ip < ind)) { minv = vp; ind = ip; }
    }

    if (!active) return;

    const float4 mb = sbox[ind];
    const size_t o4 = (size_t)b * L + i;

    if (k == 0) {
        // cls + reg targets
        out[o4] = (minv == INF_F) ? NUM_CLASSES_F : sclsf[ind];
        float4* reg4 = reinterpret_cast<float4*>(out + (size_t)B * L) + o4;
        *reg4 = make_float4(x - mb.x, y - mb.y, mb.z - x, mb.w - y);
    } else if (k == 1) {
        // deltas (div/log heavy) on lane 1; anchors load exec-masked to k==1
        const float4 an = reinterpret_cast<const float4*>(anchors)[i];
        const float aw  = an.z - an.x;
        const float ah  = an.w - an.y;
        const float acx = an.x + 0.5f * aw;
        const float acy = an.y + 0.5f * ah;
        const float gw  = mb.z - mb.x;
        const float gh  = mb.w - mb.y;
        const float gcx = mb.x + 0.5f * gw;
        const float gcy = mb.y + 0.5f * gh;

        float4* del4 = reinterpret_cast<float4*>(out + (size_t)B * L * 5) + o4;
        *del4 = make_float4((gcx - acx) / aw, (gcy - acy) / ah,
                            logf(gw / aw), logf(gh / ah));
    }
}

extern "C" void kernel_launch(void* const* d_in, const int* in_sizes, int n_in,
                              void* d_out, int out_size, void* d_ws, size_t ws_size,
                              hipStream_t stream) {
    const float* locations = (const float*)d_in[0];
    const float* strides   = (const float*)d_in[1];
    const float* soi       = (const float*)d_in[2];
    const float* anchors   = (const float*)d_in[3];
    const float* gt_boxes  = (const float*)d_in[4];
    const int*   gt_cls    = (const int*)d_in[5];
    float* out = (float*)d_out;

    const int L = in_sizes[1];            // strides_per_loc has L elements
    const int B = in_sizes[5] / NGT;      // gt_classes has B*G elements

    dim3 grid((L + 63) / 64, B);          // 64 locations per 256-thread block
    fcos_match_kernel<<<grid, dim3(256), 0, stream>>>(locations, strides, soi, anchors,
                                                      gt_boxes, gt_cls, out, L, B);
}

// Round 7
// 14.093 us; speedup vs baseline: 1.0821x; 1.0821x over previous
//
#include <hip/hip_runtime.h>

#define NGT 64
#define NUM_CLASSES_F 80.0f
#define INF_F 100000000.0f
#define RADIUS_F 1.5f

__global__ __launch_bounds__(256, 8) void fcos_match_kernel(
    const float* __restrict__ locations,      // (L,2)
    const float* __restrict__ strides_per_loc,// (L,)
    const float* __restrict__ soi,            // (L,2)
    const float* __restrict__ anchors,        // (L,4)
    const float* __restrict__ gt_boxes,       // (B,G,4)
    const int*   __restrict__ gt_classes,     // (B,G)
    float* __restrict__ out,                  // cls (B*L) | reg (B*L*4) | deltas (B*L*4)
    int L, int B)
{
    const int b   = blockIdx.y;
    const int tid = threadIdx.x;

    __shared__ float4 sbox[NGT];   // {x1,y1,x2,y2}
    __shared__ float4 sbd[NGT];    // {ccx, ccy, rank_bits, clsf}
    __shared__ float  sarea[NGT];
    __shared__ int    sinv[NGT];   // rank -> box index

    // Phase A: load boxes, derived values.
    if (tid < NGT) {
        const float4 bx = reinterpret_cast<const float4*>(gt_boxes)[b * NGT + tid];
        sbox[tid]  = bx;
        sarea[tid] = (bx.z - bx.x) * (bx.w - bx.y);
        sbd[tid]   = make_float4((bx.x + bx.z) * 0.5f,   // same expr as R4-R6 (absmax 0.0)
                                 (bx.y + bx.w) * 0.5f,
                                 0.0f,
                                 (float)gt_classes[b * NGT + tid]);
    }
    __syncthreads();

    // Phase B: rank boxes by (area, j) lexicographic; 4 threads per box.
    {
        const int j  = tid >> 2;
        const int kk = tid & 3;
        const float aj = sarea[j];
        int cnt = 0;
        #pragma unroll
        for (int it = 0; it < 16; ++it) {
            const int kb = (kk << 4) + it;
            const float ak = sarea[kb];
            cnt += ((ak < aj) || (ak == aj && kb < j)) ? 1 : 0;
        }
        cnt += __shfl_xor(cnt, 1);   // pairs share j
        cnt += __shfl_xor(cnt, 2);
        if (kk == 0) {
            reinterpret_cast<float*>(&sbd[j])[2] = __uint_as_float((unsigned)cnt);
            sinv[cnt] = j;           // ranks are a permutation (strict total order)
        }
    }
    __syncthreads();

    // Main: 4 threads per location; thread k scans boxes j = 4s+k.
    const int  k      = tid & 3;
    const int  p      = blockIdx.x * 64 + (tid >> 2);
    const bool active = p < L;
    const int  i      = active ? p : 0;

    const float2 xy   = reinterpret_cast<const float2*>(locations)[i];
    const float  x    = xy.x, y = xy.y;
    const float  rad  = strides_per_loc[i] * RADIUS_F;
    const float2 lohi = reinterpret_cast<const float2*>(soi)[i];

    unsigned mnr = 0xFFu;            // sentinel rank = no valid box

    #pragma unroll
    for (int s = 0; s < 16; ++s) {
        const int jg = (s << 2) | k;
        const float4 bx = sbox[jg];
        const float4 bd = sbd[jg];

        const float l = x - bx.x, t = y - bx.y;
        const float r = bx.z - x, d = bx.w - y;
        const float mx = fmaxf(fmaxf(fmaxf(l, t), r), d);   // max3+max
        const float mn = fminf(fminf(fminf(l, t), r), d);   // min3+min

        const float cx = rad - fabsf(x - bd.x);             // validated rounding path
        const float cy = rad - fabsf(y - bd.y);
        const float cmin = fminf(fminf(mn, cx), cy);        // min3

        const float g = fminf(mx - lohi.x, lohi.y - mx);
        const bool valid = (cmin > 0.0f) && (g >= 0.0f);

        const unsigned rk = valid ? __float_as_uint(bd.z) : 0xFFu;
        mnr = min(mnr, rk);          // single loop-carried op
    }

    // Reduce min-rank over the 4-lane group.
    mnr = min(mnr, (unsigned)__shfl_xor((int)mnr, 1));
    mnr = min(mnr, (unsigned)__shfl_xor((int)mnr, 2));

    if (!active) return;

    const bool none = (mnr == 0xFFu);
    const int  ind  = none ? 0 : sinv[mnr];   // all-invalid -> argmin(all INF) = 0
    const float4 mb = sbox[ind];
    const size_t o4 = (size_t)b * L + i;

    if (k == 0) {
        out[o4] = none ? NUM_CLASSES_F : sbd[ind].w;
        float4* reg4 = reinterpret_cast<float4*>(out + (size_t)B * L) + o4;
        *reg4 = make_float4(x - mb.x, y - mb.y, mb.z - x, mb.w - y);
    } else if (k == 1) {
        const float4 an = reinterpret_cast<const float4*>(anchors)[i];
        const float aw  = an.z - an.x;
        const float ah  = an.w - an.y;
        const float acx = an.x + 0.5f * aw;
        const float acy = an.y + 0.5f * ah;
        const float gw  = mb.z - mb.x;
        const float gh  = mb.w - mb.y;
        const float gcx = mb.x + 0.5f * gw;
        const float gcy = mb.y + 0.5f * gh;

        float4* del4 = reinterpret_cast<float4*>(out + (size_t)B * L * 5) + o4;
        *del4 = make_float4((gcx - acx) / aw, (gcy - acy) / ah,
                            logf(gw / aw), logf(gh / ah));
    }
}

extern "C" void kernel_launch(void* const* d_in, const int* in_sizes, int n_in,
                              void* d_out, int out_size, void* d_ws, size_t ws_size,
                              hipStream_t stream) {
    const float* locations = (const float*)d_in[0];
    const float* strides   = (const float*)d_in[1];
    const float* soi       = (const float*)d_in[2];
    const float* anchors   = (const float*)d_in[3];
    const float* gt_boxes  = (const float*)d_in[4];
    const int*   gt_cls    = (const int*)d_in[5];
    float* out = (float*)d_out;

    const int L = in_sizes[1];            // strides_per_loc has L elements
    const int B = in_sizes[5] / NGT;      // gt_classes has B*G elements

    dim3 grid((L + 63) / 64, B);          // 64 locations per 256-thread block
    fcos_match_kernel<<<grid, dim3(256), 0, stream>>>(locations, strides, soi, anchors,
                                                      gt_boxes, gt_cls, out, L, B);
}